// Round 13
// baseline (741.907 us; speedup 1.0000x reference)
//
#include <hip/hip_runtime.h>
#include <cstdint>

#define C_LEN 4096
#define E_DIM 1024
#define NBATCH 4

typedef __attribute__((ext_vector_type(4))) float f32x4;
typedef __attribute__((ext_vector_type(8))) short bf16x8;
typedef __attribute__((ext_vector_type(4))) unsigned short u16x4;

__device__ __forceinline__ unsigned short f2bf(float f) {
  uint32_t u = __builtin_bit_cast(uint32_t, f);
  return (unsigned short)((u + 0x7fffu + ((u >> 16) & 1u)) >> 16);
}

__device__ __forceinline__ void gl_lds16(const void* g, void* l) {
  __builtin_amdgcn_global_load_lds(
      (const __attribute__((address_space(1))) void*)g,
      (__attribute__((address_space(3))) void*)l, 16, 0, 0);
}

#define BAR() __builtin_amdgcn_s_barrier()
#define LGKM0() do { asm volatile("s_waitcnt lgkmcnt(0)" ::: "memory"); \
                     __builtin_amdgcn_sched_barrier(0); } while (0)
#define VMC(n) asm volatile("s_waitcnt vmcnt(" #n ")" ::: "memory")

// -------- RoPE cos/sin table: [C][E/2] f32 each --------
__global__ __launch_bounds__(256) void rope_table(float* __restrict__ cosT,
                                                  float* __restrict__ sinT) {
  int idx = blockIdx.x * 256 + threadIdx.x;  // over C*E/2
  int pos = idx >> 9;
  int i = idx & 511;
  double inv = exp(((double)(-2 * i) / 1024.0) * 9.210340371976184);
  double a = (double)pos * inv;
  double r = a - 6.283185307179586 * rint(a * 0.15915494309189535);
  float rf = (float)r;
  float s, c;
  __sincosf(rf, &s, &c);
  cosT[idx] = c;
  sinT[idx] = s;
}

// -------- fused f32 -> bf16 convert for x, Wq, Wk, Wv --------
__global__ __launch_bounds__(256) void cvt_all(const float* __restrict__ x,
                                               const float* __restrict__ wq,
                                               const float* __restrict__ wk,
                                               const float* __restrict__ wv,
                                               unsigned short* __restrict__ x_bf,
                                               unsigned short* __restrict__ w_bf) {
  int b = blockIdx.x;
  const float* in;
  unsigned short* out;
  long off;
  if (b < 16384) { in = x; out = x_bf; off = (long)b * 1024; }
  else if (b < 17408) { in = wq; out = w_bf; off = (long)(b - 16384) * 1024; }
  else if (b < 18432) { in = wk; out = w_bf + (1l << 20); off = (long)(b - 17408) * 1024; }
  else { in = wv; out = w_bf + (2l << 20); off = (long)(b - 18432) * 1024; }
  long i = off + threadIdx.x * 4;
  f32x4 v = *(const f32x4*)(in + i);
  u16x4 o = {f2bf(v.x), f2bf(v.y), f2bf(v.z), f2bf(v.w)};
  *(u16x4*)(out + i) = o;
}

// ======== 256x256 8-phase GEMM (r12 loop body, PERSISTENT multi-rep) ========
// 512 threads = 8 waves (2M x 4N). LDS 128 KiB [buf(2)][A/B][half][128][64].
// Per rep: prologue-stage both K-tiles -> vmcnt(8) (also retires prior rep's
// epilogue stores) -> 8-phase K-loop (unchanged from r12) -> epilogue stores
// fire-and-forget; next rep's K-loop overlaps the store drain. Race-free: all
// LDS reads are LGKM0-drained before the barrier preceding ph8's MFMA, after
// which no wave touches LDS until next-rep staging.
// MODE 0: fused QKV projection (reps over 768 tile space); RoPE Q/K, transp V.
// MODE 2: scores (*1/32 + mask); rep = batch, fixed (rt,ct) per block so the
//         mask tile is fetched once and L2-hits for reps 1-3.
// MODE 3: plain f32 out (PV), reps=1.
template <int MODE>
__global__ __launch_bounds__(512, 1) void gemm8(
    const unsigned short* __restrict__ A, const unsigned short* __restrict__ Bm,
    long sAb, long sBb, long sOb, int nr, int nc, int K, int N, int reps,
    unsigned short* __restrict__ oQ, unsigned short* __restrict__ oK,
    unsigned short* __restrict__ oVt, float* __restrict__ oF,
    const float* __restrict__ cosT, const float* __restrict__ sinT,
    const float* __restrict__ mask) {
  __shared__ unsigned short lds[2][2][2][128 * 64];  // 128 KiB
  const int tid = threadIdx.x;
  const int lane = tid & 63;
  const int wid = tid >> 6;
  const int wm = wid >> 2, wn = wid & 3;  // 2M x 4N
  const int kgrp = lane >> 4, r16 = lane & 15;

  // XCD chunk on the physical grid (nwg%8==0)
  const int nwg = gridDim.x;
  const int lid = blockIdx.x;
  const int sw = (lid & 7) * (nwg >> 3) + (lid >> 3);

  for (int rep = 0; rep < reps; ++rep) {
    int bz, rt, ct;
    if (MODE == 2) {
      // fixed (rt,ct) per block from sw; batch = rep (mask tile reused)
      bz = rep;
      const int scc = nc >> 2;
      const int sid = sw >> 4, inner = sw & 15;
      const int srt = sid / scc, sct = sid - srt * scc;
      rt = srt * 4 + (inner >> 2);
      ct = sct * 4 + (inner & 3);
    } else {
      const int s = rep * nwg + sw;
      const int scc = nc >> 2;
      const int per_b_st = (nr >> 2) * scc;
      const int sid = s >> 4, inner = s & 15;
      bz = sid / per_b_st;
      const int r2 = sid - bz * per_b_st;
      const int srt = r2 / scc, sct = r2 - srt * scc;
      rt = srt * 4 + (inner >> 2);
      ct = sct * 4 + (inner & 3);
    }

    const unsigned short* Ag = A + sAb * bz + (long)rt * 256 * K;
    const unsigned short* Bg = Bm + sBb * bz + (long)ct * 256 * K;

    // stage one half-tile (128x64) = 2 gl_lds/thread; LDS linear, src col
    // granule inverse-swizzled by the read involution (g ^= row&7).
    auto stA = [&](int buf, int half, int t) {
#pragma unroll
      for (int q = 0; q < 2; ++q) {
        int G = q * 512 + tid;
        int r = G >> 3, g = G & 7;
        gl_lds16(Ag + (long)(half * 128 + r) * K + t * 64 + ((g ^ (r & 7)) << 3),
                 &lds[buf][0][half][G * 8]);
      }
    };
    auto stB = [&](int buf, int half, int t) {
#pragma unroll
      for (int q = 0; q < 2; ++q) {
        int G = q * 512 + tid;
        int r = G >> 3, g = G & 7;
        gl_lds16(Bg + (long)(half * 128 + r) * K + t * 64 + ((g ^ (r & 7)) << 3),
                 &lds[buf][1][half][G * 8]);
      }
    };

    f32x4 acc[8][4];
#pragma unroll
    for (int m = 0; m < 8; ++m)
#pragma unroll
      for (int n = 0; n < 4; ++n) acc[m][n] = {0.f, 0.f, 0.f, 0.f};

    bf16x8 aF[8], bF0[4], bF1[4];
    auto rdA = [&](int buf, int mh) {
#pragma unroll
      for (int m = 0; m < 4; ++m) {
        int row = mh * 64 + m * 16 + r16;
#pragma unroll
        for (int ks = 0; ks < 2; ++ks)
          aF[m * 2 + ks] = *(const bf16x8*)&lds[buf][0][wm]
              [row * 64 + ((((ks << 2) + kgrp) ^ (row & 7)) << 3)];
      }
    };
    auto rdB = [&](int buf, int nh, bf16x8* d) {
#pragma unroll
      for (int n = 0; n < 2; ++n) {
        int row = (wn & 1) * 64 + nh * 32 + n * 16 + r16;
#pragma unroll
        for (int ks = 0; ks < 2; ++ks)
          d[n * 2 + ks] = *(const bf16x8*)&lds[buf][1][wn >> 1]
              [row * 64 + ((((ks << 2) + kgrp) ^ (row & 7)) << 3)];
      }
    };
    auto mm = [&](bf16x8* bf, int mh, int nh) {
      __builtin_amdgcn_s_setprio(1);
#pragma unroll
      for (int ks = 0; ks < 2; ++ks)
#pragma unroll
        for (int m = 0; m < 4; ++m)
#pragma unroll
          for (int n = 0; n < 2; ++n)
            acc[mh * 4 + m][nh * 2 + n] = __builtin_amdgcn_mfma_f32_16x16x32_bf16(
                aF[m * 2 + ks], bf[n * 2 + ks], acc[mh * 4 + m][nh * 2 + n], 0, 0, 0);
      __builtin_amdgcn_s_setprio(0);
    };

    const int NIT = K >> 7;  // 2 K-tiles (BK=64) per iteration
    // Prologue: tiles 0 (buf0) and 1 (buf1) fully staged. VMC(8) retires tile
    // 0's loads AND any still-outstanding stores from the previous rep.
    stA(0, 0, 0); stA(0, 1, 0); stB(0, 0, 0); stB(0, 1, 0);
    stA(1, 0, 1); stA(1, 1, 1); stB(1, 0, 1); stB(1, 1, 1);
    VMC(8);
    BAR();
    __builtin_amdgcn_sched_barrier(0);

    for (int it = 0; it < NIT; ++it) {
      const int t1 = 2 * it + 1, t2 = 2 * it + 2, t3 = 2 * it + 3;
      const bool more = (it + 1 < NIT);
      // ---- ph1: t0 (mh0,nh0) ---- buf1-A sealed at prev ph7
      rdA(0, 0); rdB(0, 0, bF0);
      if (it > 0) stA(1, 0, t1);
      BAR(); LGKM0();
      mm(bF0, 0, 0);
      BAR();
      // ---- ph2: t0 (mh0,nh1) ----
      rdB(0, 1, bF1);
      if (it > 0) stA(1, 1, t1);
      BAR(); LGKM0();
      mm(bF1, 0, 1);
      BAR();
      // ---- ph3: t0 (mh1,nh1) ---- buf0-B sealed at ph2 end
      rdA(0, 1);
      if (more) stB(0, 0, t2);
      BAR(); LGKM0();
      mm(bF1, 1, 1);
      BAR();
      // ---- ph4: t0 (mh1,nh0) ---- vmcnt: tile t1 fully landed for ph5
      if (more) stB(0, 1, t2);
      BAR();
      mm(bF0, 1, 0);
      if (more) { VMC(4); } else { VMC(0); }
      BAR();
      // ---- ph5: t1 (mh0,nh0) ---- buf0-A sealed at ph3 end
      rdA(1, 0); rdB(1, 0, bF0);
      if (more) stA(0, 0, t2);
      BAR(); LGKM0();
      mm(bF0, 0, 0);
      BAR();
      // ---- ph6: t1 (mh0,nh1) ----
      rdB(1, 1, bF1);
      if (more) stA(0, 1, t2);
      BAR(); LGKM0();
      mm(bF1, 0, 1);
      BAR();
      // ---- ph7: t1 (mh1,nh1) ---- buf1-B sealed at ph6 end
      rdA(1, 1);
      if (more) stB(1, 0, t3);
      BAR(); LGKM0();
      mm(bF1, 1, 1);
      BAR();
      // ---- ph8: t1 (mh1,nh0) ---- vmcnt: tile t2 fully landed for next ph1
      if (more) stB(1, 1, t3);
      BAR();
      mm(bF0, 1, 0);
      if (more) { VMC(4); BAR(); }
    }

    // Epilogue: stores fire-and-forget; next rep's prologue VMC(8) drains them.
    const int row0 = rt * 256 + wm * 128;
    const int col0 = ct * 256 + wn * 64;
#pragma unroll
    for (int m = 0; m < 8; ++m) {
#pragma unroll
      for (int n = 0; n < 4; ++n) {
#pragma unroll
        for (int r = 0; r < 4; ++r) {
          float v = acc[m][n][r];
          int row = row0 + m * 16 + kgrp * 4 + r;  // C/D: col=lane&15, row=(lane>>4)*4+r
          int col = col0 + n * 16 + r16;
          if (MODE == 0) {
            float pp = __shfl_xor(v, 1);  // RoPE pair partner (col^1, same row/reg)
            int sel = col >> 10;          // 0=Q 1=K 2=V (uniform per 64-col wave slice)
            int lcol = col & 1023;
            if (sel < 2) {
              int pos = row & (C_LEN - 1);
              int i2 = lcol >> 1;
              float c = cosT[pos * (E_DIM / 2) + i2];
              float sn = sinT[pos * (E_DIM / 2) + i2];
              float rv = v * c + ((lcol & 1) ? pp * sn : -pp * sn);
              unsigned short* o = sel ? oK : oQ;
              o[(long)row * E_DIM + lcol] = f2bf(rv);
            } else {
              int b = row >> 12;
              int cc = row & (C_LEN - 1);
              oVt[(long)b * E_DIM * C_LEN + (long)lcol * C_LEN + cc] = f2bf(v);
            }
          } else if (MODE == 2) {
            float sc = v * 0.03125f + mask[(long)row * C_LEN + col];
            oF[sOb * bz + (long)row * C_LEN + col] = sc;
          } else {
            oF[sOb * bz + (long)row * N + col] = v;
          }
        }
      }
    }
  }
}

// -------- row softmax: normalize f32 weights in place + emit bf16 copy --------
__global__ __launch_bounds__(256) void softmax_rows(float* __restrict__ w,
                                                    unsigned short* __restrict__ pb) {
  long row = blockIdx.x;
  float* p = w + row * C_LEN;
  unsigned short* pbp = pb + row * C_LEN;
  int t = threadIdx.x;
  int wid = t >> 6;
  f32x4 v[4];
  float mx = -3.4e38f;
#pragma unroll
  for (int j = 0; j < 4; ++j) {
    v[j] = __builtin_nontemporal_load((const f32x4*)(p + j * 1024 + t * 4));
    mx = fmaxf(mx, fmaxf(fmaxf(v[j].x, v[j].y), fmaxf(v[j].z, v[j].w)));
  }
#pragma unroll
  for (int o = 1; o < 64; o <<= 1) mx = fmaxf(mx, __shfl_xor(mx, o));
  __shared__ float redm[4];
  if ((t & 63) == 0) redm[wid] = mx;
  __syncthreads();
  mx = fmaxf(fmaxf(redm[0], redm[1]), fmaxf(redm[2], redm[3]));
  float sum = 0.f;
#pragma unroll
  for (int j = 0; j < 4; ++j) {
    v[j].x = __expf(v[j].x - mx);
    v[j].y = __expf(v[j].y - mx);
    v[j].z = __expf(v[j].z - mx);
    v[j].w = __expf(v[j].w - mx);
    sum += v[j].x + v[j].y + v[j].z + v[j].w;
  }
#pragma unroll
  for (int o = 1; o < 64; o <<= 1) sum += __shfl_xor(sum, o);
  __shared__ float reds[4];
  if ((t & 63) == 0) reds[wid] = sum;
  __syncthreads();
  sum = reds[0] + reds[1] + reds[2] + reds[3];
  float inv = 1.0f / sum;
#pragma unroll
  for (int j = 0; j < 4; ++j) {
    v[j].x *= inv;
    v[j].y *= inv;
    v[j].z *= inv;
    v[j].w *= inv;
    __builtin_nontemporal_store(v[j], (f32x4*)(p + j * 1024 + t * 4));
    u16x4 o16 = {f2bf(v[j].x), f2bf(v[j].y), f2bf(v[j].z), f2bf(v[j].w)};
    *(u16x4*)(pbp + j * 1024 + t * 4) = o16;
  }
}

extern "C" void kernel_launch(void* const* d_in, const int* in_sizes, int n_in,
                              void* d_out, int out_size, void* d_ws, size_t ws_size,
                              hipStream_t stream) {
  const float* x = (const float*)d_in[0];
  const float* mask = (const float*)d_in[1];
  const float* Wq = (const float*)d_in[2];
  const float* Wk = (const float*)d_in[3];
  const float* Wv = (const float*)d_in[4];
  float* out = (float*)d_out;                           // [B][C][E]
  float* weights = out + (long)NBATCH * C_LEN * E_DIM;  // [B][C][C]

  char* ws = (char*)d_ws;
  const bool big = ws_size >= (160ull << 20);
  float* cosT = (float*)(ws);
  float* sinT = (float*)(ws + (8l << 20));
  unsigned short* x_bf = (unsigned short*)(ws + (16l << 20));
  unsigned short* W_bf = (unsigned short*)(ws + (48l << 20));  // [3072][1024] = Q|K|V
  unsigned short* Q_bf = (unsigned short*)(ws + (54l << 20));
  unsigned short* K_bf = (unsigned short*)(ws + (86l << 20));
  unsigned short* Vt = (unsigned short*)(ws + (big ? (128l << 20) : (118l << 20)));
  unsigned short* P_bf = (unsigned short*)(ws);

  dim3 blk(256);
  dim3 blk512(512);

  rope_table<<<dim3((C_LEN * (E_DIM / 2)) / 256), blk, 0, stream>>>(cosT, sinT);
  cvt_all<<<dim3(19456), blk, 0, stream>>>(x, Wq, Wk, Wv, x_bf, W_bf);

  // fused QKV projection: 768 tiles as 256 persistent blocks x 3 reps
  gemm8<0><<<dim3(256), blk512, 0, stream>>>(
      x_bf, W_bf, 0, 0, 0, 64, 12, E_DIM, 3 * E_DIM, 3,
      Q_bf, K_bf, Vt, nullptr, cosT, sinT, nullptr);

  // scores = QK^T/32 + mask: 256 persistent blocks x 4 reps (rep = batch;
  // fixed (rt,ct) per block -> mask tile fetched once)
  gemm8<2><<<dim3(256), blk512, 0, stream>>>(
      Q_bf, K_bf, (long)C_LEN * E_DIM, (long)C_LEN * E_DIM, (long)C_LEN * C_LEN,
      16, 16, E_DIM, C_LEN, 4, nullptr, nullptr, nullptr, weights, nullptr, nullptr, mask);

  if (big) {
    softmax_rows<<<dim3(NBATCH * C_LEN), blk, 0, stream>>>(weights, P_bf);
    // out = P @ V: 16 rt x 4 ct x 4 bz = 256 blocks, 1 rep
    gemm8<3><<<dim3(256), blk512, 0, stream>>>(
        P_bf, Vt, (long)C_LEN * C_LEN, (long)E_DIM * C_LEN, (long)C_LEN * E_DIM,
        16, 4, C_LEN, E_DIM, 1, nullptr, nullptr, nullptr, out, nullptr, nullptr, nullptr);
  } else {
    for (int h = 0; h < 2; ++h) {
      float* wgt = weights + (long)h * 2 * C_LEN * C_LEN;
      softmax_rows<<<dim3(2 * C_LEN), blk, 0, stream>>>(wgt, P_bf);
      gemm8<3><<<dim3(128), blk512, 0, stream>>>(
          P_bf, Vt + (long)h * 2 * E_DIM * C_LEN, (long)C_LEN * C_LEN, (long)E_DIM * C_LEN,
          (long)C_LEN * E_DIM, 16, 4, C_LEN, E_DIM, 1,
          nullptr, nullptr, nullptr, out + (long)h * 2 * C_LEN * E_DIM,
          nullptr, nullptr, nullptr);
    }
  }
}

// Round 14
// 591.885 us; speedup vs baseline: 1.2535x; 1.2535x over previous
//
#include <hip/hip_runtime.h>
#include <cstdint>

#define C_LEN 4096
#define E_DIM 1024
#define NBATCH 4

typedef __attribute__((ext_vector_type(4))) float f32x4;
typedef __attribute__((ext_vector_type(8))) short bf16x8;
typedef __attribute__((ext_vector_type(4))) unsigned short u16x4;

__device__ __forceinline__ unsigned short f2bf(float f) {
  uint32_t u = __builtin_bit_cast(uint32_t, f);
  return (unsigned short)((u + 0x7fffu + ((u >> 16) & 1u)) >> 16);
}

__device__ __forceinline__ unsigned short f2h(float f) {
  _Float16 h = (_Float16)f;
  return __builtin_bit_cast(unsigned short, h);
}
__device__ __forceinline__ float h2f(unsigned short u) {
  return (float)__builtin_bit_cast(_Float16, u);
}

__device__ __forceinline__ void gl_lds16(const void* g, void* l) {
  __builtin_amdgcn_global_load_lds(
      (const __attribute__((address_space(1))) void*)g,
      (__attribute__((address_space(3))) void*)l, 16, 0, 0);
}

#define BAR() __builtin_amdgcn_s_barrier()
#define LGKM0() do { asm volatile("s_waitcnt lgkmcnt(0)" ::: "memory"); \
                     __builtin_amdgcn_sched_barrier(0); } while (0)
#define VMC(n) asm volatile("s_waitcnt vmcnt(" #n ")" ::: "memory")

// -------- RoPE cos/sin table: [C][E/2] f32 each --------
__global__ __launch_bounds__(256) void rope_table(float* __restrict__ cosT,
                                                  float* __restrict__ sinT) {
  int idx = blockIdx.x * 256 + threadIdx.x;  // over C*E/2
  int pos = idx >> 9;
  int i = idx & 511;
  double inv = exp(((double)(-2 * i) / 1024.0) * 9.210340371976184);
  double a = (double)pos * inv;
  double r = a - 6.283185307179586 * rint(a * 0.15915494309189535);
  float rf = (float)r;
  float s, c;
  __sincosf(rf, &s, &c);
  cosT[idx] = c;
  sinT[idx] = s;
}

// -------- fused f32 -> bf16 convert for x, Wq, Wk, Wv --------
__global__ __launch_bounds__(256) void cvt_all(const float* __restrict__ x,
                                               const float* __restrict__ wq,
                                               const float* __restrict__ wk,
                                               const float* __restrict__ wv,
                                               unsigned short* __restrict__ x_bf,
                                               unsigned short* __restrict__ w_bf) {
  int b = blockIdx.x;
  const float* in;
  unsigned short* out;
  long off;
  if (b < 16384) { in = x; out = x_bf; off = (long)b * 1024; }
  else if (b < 17408) { in = wq; out = w_bf; off = (long)(b - 16384) * 1024; }
  else if (b < 18432) { in = wk; out = w_bf + (1l << 20); off = (long)(b - 17408) * 1024; }
  else { in = wv; out = w_bf + (2l << 20); off = (long)(b - 18432) * 1024; }
  long i = off + threadIdx.x * 4;
  f32x4 v = *(const f32x4*)(in + i);
  u16x4 o = {f2bf(v.x), f2bf(v.y), f2bf(v.z), f2bf(v.w)};
  *(u16x4*)(out + i) = o;
}

// ======== 256x256 8-phase GEMM (r12 structure = best measured), BK=64 ========
// 512 threads = 8 waves (2M x 4N). LDS 128 KiB [buf(2)][A/B][half][128][64].
// Phase = {ds-reads || stage 1 half-tile -> barrier -> lgkm0 -> setprio MFMA
// -> barrier}; vmcnt(4) only at ph4/ph8. Swizzle: granule ^= row&7 (0
// conflicts), inverse-permuted global src + linear gl_lds dest. XCD chunk +
// 4x4 supertile; MODE 2 batch-innermost (mask tile L2 shared).
// MODE 0: fused QKV projection (N=3072=[Q|K|V]); RoPE on Q/K, transpose V.
// MODE 2: *1/32 + mask, stores **f16** scores packed into the FIRST 8 KB of
//         each output row's 16 KB f32 slot (row-local; softmax reads its own
//         row before overwriting -> race-free, halves intermediate traffic).
// MODE 3: plain f32 out (PV).
template <int MODE>
__global__ __launch_bounds__(512, 1) void gemm8(
    const unsigned short* __restrict__ A, const unsigned short* __restrict__ Bm,
    long sAb, long sBb, long sOb, int nr, int nc, int K, int N,
    unsigned short* __restrict__ oQ, unsigned short* __restrict__ oK,
    unsigned short* __restrict__ oVt, float* __restrict__ oF,
    const float* __restrict__ cosT, const float* __restrict__ sinT,
    const float* __restrict__ mask) {
  __shared__ unsigned short lds[2][2][2][128 * 64];  // 128 KiB
  const int tid = threadIdx.x;
  const int lane = tid & 63;
  const int wid = tid >> 6;
  const int wm = wid >> 2, wn = wid & 3;  // 2M x 4N
  const int kgrp = lane >> 4, r16 = lane & 15;

  // XCD chunk (nwg%8==0) + 4x4 supertile decode (nr%4==0, nc%4==0)
  const int nwg = gridDim.x;
  const int lid = blockIdx.x;
  const int s = (lid & 7) * (nwg >> 3) + (lid >> 3);
  int bz, rt, ct;
  if (MODE == 2) {
    // batch innermost: 4 consecutive same-XCD blocks share (rt,ct) mask tile
    bz = s & 3;
    const int s4 = s >> 2;
    const int scc = nc >> 2;
    const int sid = s4 >> 4, inner = s4 & 15;
    const int srt = sid / scc, sct = sid - srt * scc;
    rt = srt * 4 + (inner >> 2);
    ct = sct * 4 + (inner & 3);
  } else {
    const int scc = nc >> 2;
    const int per_b_st = (nr >> 2) * scc;
    const int sid = s >> 4, inner = s & 15;
    bz = sid / per_b_st;
    const int r2 = sid - bz * per_b_st;
    const int srt = r2 / scc, sct = r2 - srt * scc;
    rt = srt * 4 + (inner >> 2);
    ct = sct * 4 + (inner & 3);
  }

  const unsigned short* Ag = A + sAb * bz + (long)rt * 256 * K;
  const unsigned short* Bg = Bm + sBb * bz + (long)ct * 256 * K;

  // stage one half-tile (128x64) = 2 gl_lds/thread; LDS linear, src col
  // granule inverse-swizzled by the read involution (g ^= row&7).
  auto stA = [&](int buf, int half, int t) {
#pragma unroll
    for (int q = 0; q < 2; ++q) {
      int G = q * 512 + tid;
      int r = G >> 3, g = G & 7;
      gl_lds16(Ag + (long)(half * 128 + r) * K + t * 64 + ((g ^ (r & 7)) << 3),
               &lds[buf][0][half][G * 8]);
    }
  };
  auto stB = [&](int buf, int half, int t) {
#pragma unroll
    for (int q = 0; q < 2; ++q) {
      int G = q * 512 + tid;
      int r = G >> 3, g = G & 7;
      gl_lds16(Bg + (long)(half * 128 + r) * K + t * 64 + ((g ^ (r & 7)) << 3),
               &lds[buf][1][half][G * 8]);
    }
  };

  f32x4 acc[8][4];
#pragma unroll
  for (int m = 0; m < 8; ++m)
#pragma unroll
    for (int n = 0; n < 4; ++n) acc[m][n] = {0.f, 0.f, 0.f, 0.f};

  bf16x8 aF[8], bF0[4], bF1[4];
  auto rdA = [&](int buf, int mh) {
#pragma unroll
    for (int m = 0; m < 4; ++m) {
      int row = mh * 64 + m * 16 + r16;
#pragma unroll
      for (int ks = 0; ks < 2; ++ks)
        aF[m * 2 + ks] = *(const bf16x8*)&lds[buf][0][wm]
            [row * 64 + ((((ks << 2) + kgrp) ^ (row & 7)) << 3)];
    }
  };
  auto rdB = [&](int buf, int nh, bf16x8* d) {
#pragma unroll
    for (int n = 0; n < 2; ++n) {
      int row = (wn & 1) * 64 + nh * 32 + n * 16 + r16;
#pragma unroll
      for (int ks = 0; ks < 2; ++ks)
        d[n * 2 + ks] = *(const bf16x8*)&lds[buf][1][wn >> 1]
            [row * 64 + ((((ks << 2) + kgrp) ^ (row & 7)) << 3)];
    }
  };
  auto mm = [&](bf16x8* bf, int mh, int nh) {
    __builtin_amdgcn_s_setprio(1);
#pragma unroll
    for (int ks = 0; ks < 2; ++ks)
#pragma unroll
      for (int m = 0; m < 4; ++m)
#pragma unroll
        for (int n = 0; n < 2; ++n)
          acc[mh * 4 + m][nh * 2 + n] = __builtin_amdgcn_mfma_f32_16x16x32_bf16(
              aF[m * 2 + ks], bf[n * 2 + ks], acc[mh * 4 + m][nh * 2 + n], 0, 0, 0);
    __builtin_amdgcn_s_setprio(0);
  };

  const int NIT = K >> 7;  // 2 K-tiles (BK=64) per iteration
  stA(0, 0, 0); stA(0, 1, 0); stB(0, 0, 0); stB(0, 1, 0);
  stA(1, 0, 1); stA(1, 1, 1); stB(1, 0, 1); stB(1, 1, 1);
  VMC(8);
  BAR();
  __builtin_amdgcn_sched_barrier(0);

  for (int it = 0; it < NIT; ++it) {
    const int t1 = 2 * it + 1, t2 = 2 * it + 2, t3 = 2 * it + 3;
    const bool more = (it + 1 < NIT);
    // ---- ph1: t0 (mh0,nh0) ---- buf1-A sealed at prev ph7
    rdA(0, 0); rdB(0, 0, bF0);
    if (it > 0) stA(1, 0, t1);
    BAR(); LGKM0();
    mm(bF0, 0, 0);
    BAR();
    // ---- ph2: t0 (mh0,nh1) ----
    rdB(0, 1, bF1);
    if (it > 0) stA(1, 1, t1);
    BAR(); LGKM0();
    mm(bF1, 0, 1);
    BAR();
    // ---- ph3: t0 (mh1,nh1) ---- buf0-B sealed at ph2 end
    rdA(0, 1);
    if (more) stB(0, 0, t2);
    BAR(); LGKM0();
    mm(bF1, 1, 1);
    BAR();
    // ---- ph4: t0 (mh1,nh0) ---- vmcnt: tile t1 fully landed for ph5
    if (more) stB(0, 1, t2);
    BAR();
    mm(bF0, 1, 0);
    if (more) { VMC(4); } else { VMC(0); }
    BAR();
    // ---- ph5: t1 (mh0,nh0) ---- buf0-A sealed at ph3 end
    rdA(1, 0); rdB(1, 0, bF0);
    if (more) stA(0, 0, t2);
    BAR(); LGKM0();
    mm(bF0, 0, 0);
    BAR();
    // ---- ph6: t1 (mh0,nh1) ----
    rdB(1, 1, bF1);
    if (more) stA(0, 1, t2);
    BAR(); LGKM0();
    mm(bF1, 0, 1);
    BAR();
    // ---- ph7: t1 (mh1,nh1) ---- buf1-B sealed at ph6 end
    rdA(1, 1);
    if (more) stB(1, 0, t3);
    BAR(); LGKM0();
    mm(bF1, 1, 1);
    BAR();
    // ---- ph8: t1 (mh1,nh0) ---- vmcnt: tile t2 fully landed for next ph1
    if (more) stB(1, 1, t3);
    BAR();
    mm(bF0, 1, 0);
    if (more) { VMC(4); BAR(); }
  }

  const int row0 = rt * 256 + wm * 128;
  const int col0 = ct * 256 + wn * 64;
#pragma unroll
  for (int m = 0; m < 8; ++m) {
#pragma unroll
    for (int n = 0; n < 4; ++n) {
#pragma unroll
      for (int r = 0; r < 4; ++r) {
        float v = acc[m][n][r];
        int row = row0 + m * 16 + kgrp * 4 + r;  // C/D: col=lane&15, row=(lane>>4)*4+r
        int col = col0 + n * 16 + r16;
        if (MODE == 0) {
          float pp = __shfl_xor(v, 1);  // RoPE pair partner (col^1, same row/reg)
          int sel = col >> 10;          // 0=Q 1=K 2=V (uniform per 64-col wave slice)
          int lcol = col & 1023;
          if (sel < 2) {
            int pos = row & (C_LEN - 1);
            int i2 = lcol >> 1;
            float c = cosT[pos * (E_DIM / 2) + i2];
            float sn = sinT[pos * (E_DIM / 2) + i2];
            float rv = v * c + ((lcol & 1) ? pp * sn : -pp * sn);
            unsigned short* o = sel ? oK : oQ;
            o[(long)row * E_DIM + lcol] = f2bf(rv);
          } else {
            int b = row >> 12;
            int cc = row & (C_LEN - 1);
            oVt[(long)b * E_DIM * C_LEN + (long)lcol * C_LEN + cc] = f2bf(v);
          }
        } else if (MODE == 2) {
          float sc = v * 0.03125f + mask[(long)row * C_LEN + col];
          // f16 score packed into the first 8 KB of this row's f32 slot
          unsigned short* rowp =
              (unsigned short*)(oF + sOb * bz + (long)row * C_LEN);
          rowp[col] = f2h(sc);
        } else {
          oF[sOb * bz + (long)row * N + col] = v;
        }
      }
    }
  }
}

// -------- row softmax: read f16 scores (own row's first 8 KB), write f32
// weights in place + bf16 P copy. Row-local: no cross-row hazard. --------
__global__ __launch_bounds__(256) void softmax_rows(float* __restrict__ w,
                                                    unsigned short* __restrict__ pb) {
  long row = blockIdx.x;
  float* p = w + row * C_LEN;
  const unsigned short* ph = (const unsigned short*)p;  // f16 scores
  unsigned short* pbp = pb + row * C_LEN;
  int t = threadIdx.x;
  int wid = t >> 6;
  f32x4 v[4];
  float mx = -3.4e38f;
#pragma unroll
  for (int j = 0; j < 4; ++j) {
    u16x4 hb = *(const u16x4*)(ph + j * 1024 + t * 4);
    v[j].x = h2f(hb.x);
    v[j].y = h2f(hb.y);
    v[j].z = h2f(hb.z);
    v[j].w = h2f(hb.w);
    mx = fmaxf(mx, fmaxf(fmaxf(v[j].x, v[j].y), fmaxf(v[j].z, v[j].w)));
  }
#pragma unroll
  for (int o = 1; o < 64; o <<= 1) mx = fmaxf(mx, __shfl_xor(mx, o));
  __shared__ float redm[4];
  if ((t & 63) == 0) redm[wid] = mx;
  __syncthreads();
  mx = fmaxf(fmaxf(redm[0], redm[1]), fmaxf(redm[2], redm[3]));
  float sum = 0.f;
#pragma unroll
  for (int j = 0; j < 4; ++j) {
    v[j].x = __expf(v[j].x - mx);
    v[j].y = __expf(v[j].y - mx);
    v[j].z = __expf(v[j].z - mx);
    v[j].w = __expf(v[j].w - mx);
    sum += v[j].x + v[j].y + v[j].z + v[j].w;
  }
#pragma unroll
  for (int o = 1; o < 64; o <<= 1) sum += __shfl_xor(sum, o);
  __shared__ float reds[4];
  if ((t & 63) == 0) reds[wid] = sum;
  __syncthreads();
  sum = reds[0] + reds[1] + reds[2] + reds[3];
  float inv = 1.0f / sum;
  __syncthreads();  // all reads of this row's f16 data complete before stores
#pragma unroll
  for (int j = 0; j < 4; ++j) {
    v[j].x *= inv;
    v[j].y *= inv;
    v[j].z *= inv;
    v[j].w *= inv;
    __builtin_nontemporal_store(v[j], (f32x4*)(p + j * 1024 + t * 4));
    u16x4 o16 = {f2bf(v[j].x), f2bf(v[j].y), f2bf(v[j].z), f2bf(v[j].w)};
    *(u16x4*)(pbp + j * 1024 + t * 4) = o16;
  }
}

extern "C" void kernel_launch(void* const* d_in, const int* in_sizes, int n_in,
                              void* d_out, int out_size, void* d_ws, size_t ws_size,
                              hipStream_t stream) {
  const float* x = (const float*)d_in[0];
  const float* mask = (const float*)d_in[1];
  const float* Wq = (const float*)d_in[2];
  const float* Wk = (const float*)d_in[3];
  const float* Wv = (const float*)d_in[4];
  float* out = (float*)d_out;                           // [B][C][E]
  float* weights = out + (long)NBATCH * C_LEN * E_DIM;  // [B][C][C]

  char* ws = (char*)d_ws;
  const bool big = ws_size >= (160ull << 20);
  float* cosT = (float*)(ws);
  float* sinT = (float*)(ws + (8l << 20));
  unsigned short* x_bf = (unsigned short*)(ws + (16l << 20));
  unsigned short* W_bf = (unsigned short*)(ws + (48l << 20));  // [3072][1024] = Q|K|V
  unsigned short* Q_bf = (unsigned short*)(ws + (54l << 20));
  unsigned short* K_bf = (unsigned short*)(ws + (86l << 20));
  unsigned short* Vt = (unsigned short*)(ws + (big ? (128l << 20) : (118l << 20)));
  unsigned short* P_bf = (unsigned short*)(ws);

  dim3 blk(256);
  dim3 blk512(512);

  rope_table<<<dim3((C_LEN * (E_DIM / 2)) / 256), blk, 0, stream>>>(cosT, sinT);
  cvt_all<<<dim3(19456), blk, 0, stream>>>(x, Wq, Wk, Wv, x_bf, W_bf);

  // fused QKV projection: 64 rt x 12 ct = 768 blocks
  gemm8<0><<<dim3(768), blk512, 0, stream>>>(
      x_bf, W_bf, 0, 0, 0, 64, 12, E_DIM, 3 * E_DIM,
      Q_bf, K_bf, Vt, nullptr, cosT, sinT, nullptr);

  // scores = QK^T/32 + mask -> f16 packed into weights rows; 1024 blocks
  gemm8<2><<<dim3(1024), blk512, 0, stream>>>(
      Q_bf, K_bf, (long)C_LEN * E_DIM, (long)C_LEN * E_DIM, (long)C_LEN * C_LEN,
      16, 16, E_DIM, C_LEN, nullptr, nullptr, nullptr, weights, nullptr, nullptr, mask);

  if (big) {
    softmax_rows<<<dim3(NBATCH * C_LEN), blk, 0, stream>>>(weights, P_bf);
    // out = P @ V: 16 rt x 4 ct x 4 bz = 256 blocks
    gemm8<3><<<dim3(256), blk512, 0, stream>>>(
        P_bf, Vt, (long)C_LEN * C_LEN, (long)E_DIM * C_LEN, (long)C_LEN * E_DIM,
        16, 4, C_LEN, E_DIM, nullptr, nullptr, nullptr, out, nullptr, nullptr, nullptr);
  } else {
    for (int h = 0; h < 2; ++h) {
      float* wgt = weights + (long)h * 2 * C_LEN * C_LEN;
      softmax_rows<<<dim3(2 * C_LEN), blk, 0, stream>>>(wgt, P_bf);
      gemm8<3><<<dim3(128), blk512, 0, stream>>>(
          P_bf, Vt + (long)h * 2 * E_DIM * C_LEN, (long)C_LEN * C_LEN, (long)E_DIM * C_LEN,
          (long)C_LEN * E_DIM, 16, 4, C_LEN, E_DIM,
          nullptr, nullptr, nullptr, out + (long)h * 2 * C_LEN * E_DIM,
          nullptr, nullptr, nullptr);
    }
  }
}

// Round 15
// 586.231 us; speedup vs baseline: 1.2656x; 1.0096x over previous
//
#include <hip/hip_runtime.h>
#include <cstdint>

#define C_LEN 4096
#define E_DIM 1024
#define NBATCH 4

typedef __attribute__((ext_vector_type(4))) float f32x4;
typedef __attribute__((ext_vector_type(8))) short bf16x8;
typedef __attribute__((ext_vector_type(4))) unsigned short u16x4;

__device__ __forceinline__ unsigned short f2bf(float f) {
  uint32_t u = __builtin_bit_cast(uint32_t, f);
  return (unsigned short)((u + 0x7fffu + ((u >> 16) & 1u)) >> 16);
}

__device__ __forceinline__ unsigned short f2h(float f) {
  _Float16 h = (_Float16)f;
  return __builtin_bit_cast(unsigned short, h);
}
__device__ __forceinline__ float h2f(unsigned short u) {
  return (float)__builtin_bit_cast(_Float16, u);
}

__device__ __forceinline__ void gl_lds16(const void* g, void* l) {
  __builtin_amdgcn_global_load_lds(
      (const __attribute__((address_space(1))) void*)g,
      (__attribute__((address_space(3))) void*)l, 16, 0, 0);
}

#define BAR() __builtin_amdgcn_s_barrier()
#define SB0() __builtin_amdgcn_sched_barrier(0)
#define LGKM0() do { asm volatile("s_waitcnt lgkmcnt(0)" ::: "memory"); \
                     __builtin_amdgcn_sched_barrier(0); } while (0)
#define VMC(n) asm volatile("s_waitcnt vmcnt(" #n ")" ::: "memory")

// -------- RoPE cos/sin table: [C][E/2] f32 each --------
__global__ __launch_bounds__(256) void rope_table(float* __restrict__ cosT,
                                                  float* __restrict__ sinT) {
  int idx = blockIdx.x * 256 + threadIdx.x;  // over C*E/2
  int pos = idx >> 9;
  int i = idx & 511;
  double inv = exp(((double)(-2 * i) / 1024.0) * 9.210340371976184);
  double a = (double)pos * inv;
  double r = a - 6.283185307179586 * rint(a * 0.15915494309189535);
  float rf = (float)r;
  float s, c;
  __sincosf(rf, &s, &c);
  cosT[idx] = c;
  sinT[idx] = s;
}

// -------- fused f32 -> bf16 convert for x, Wq, Wk, Wv --------
__global__ __launch_bounds__(256) void cvt_all(const float* __restrict__ x,
                                               const float* __restrict__ wq,
                                               const float* __restrict__ wk,
                                               const float* __restrict__ wv,
                                               unsigned short* __restrict__ x_bf,
                                               unsigned short* __restrict__ w_bf) {
  int b = blockIdx.x;
  const float* in;
  unsigned short* out;
  long off;
  if (b < 16384) { in = x; out = x_bf; off = (long)b * 1024; }
  else if (b < 17408) { in = wq; out = w_bf; off = (long)(b - 16384) * 1024; }
  else if (b < 18432) { in = wk; out = w_bf + (1l << 20); off = (long)(b - 17408) * 1024; }
  else { in = wv; out = w_bf + (2l << 20); off = (long)(b - 18432) * 1024; }
  long i = off + threadIdx.x * 4;
  f32x4 v = *(const f32x4*)(in + i);
  u16x4 o = {f2bf(v.x), f2bf(v.y), f2bf(v.z), f2bf(v.w)};
  *(u16x4*)(out + i) = o;
}

// ======== 256x256 8-phase GEMM, BK=64 — r14 structure + TAIL-READ overlap ========
// 512 threads = 8 waves (2M x 4N). LDS 128 KiB [buf(2)][A/B][half][128][64].
// New vs r14: each phase's ds_reads (where the source buffer-half is already
// sealed) are issued at the TAIL of the previous phase, right after its MFMA
// cluster — the reads execute on the LDS pipe while the MFMA pipe drains.
// Only ONE extra fragment set (aF2 for mh1) is needed; bF1's tail read
// conflicts with nothing. Tile-boundary reads (ph1/ph5 tops) stay after the
// seal barrier. Staging/vmcnt ledger byte-identical to r12/r14.
// MODE 0: fused QKV projection (N=3072=[Q|K|V]); RoPE on Q/K, transpose V.
// MODE 2: *1/32 + mask, f16 scores packed into first 8KB of each f32 row slot.
// MODE 3: plain f32 out (PV).
template <int MODE>
__global__ __launch_bounds__(512, 1) void gemm8(
    const unsigned short* __restrict__ A, const unsigned short* __restrict__ Bm,
    long sAb, long sBb, long sOb, int nr, int nc, int K, int N,
    unsigned short* __restrict__ oQ, unsigned short* __restrict__ oK,
    unsigned short* __restrict__ oVt, float* __restrict__ oF,
    const float* __restrict__ cosT, const float* __restrict__ sinT,
    const float* __restrict__ mask) {
  __shared__ unsigned short lds[2][2][2][128 * 64];  // 128 KiB
  const int tid = threadIdx.x;
  const int lane = tid & 63;
  const int wid = tid >> 6;
  const int wm = wid >> 2, wn = wid & 3;  // 2M x 4N
  const int kgrp = lane >> 4, r16 = lane & 15;

  // XCD chunk (nwg%8==0) + 4x4 supertile decode (nr%4==0, nc%4==0)
  const int nwg = gridDim.x;
  const int lid = blockIdx.x;
  const int s = (lid & 7) * (nwg >> 3) + (lid >> 3);
  int bz, rt, ct;
  if (MODE == 2) {
    // batch innermost: 4 consecutive same-XCD blocks share (rt,ct) mask tile
    bz = s & 3;
    const int s4 = s >> 2;
    const int scc = nc >> 2;
    const int sid = s4 >> 4, inner = s4 & 15;
    const int srt = sid / scc, sct = sid - srt * scc;
    rt = srt * 4 + (inner >> 2);
    ct = sct * 4 + (inner & 3);
  } else {
    const int scc = nc >> 2;
    const int per_b_st = (nr >> 2) * scc;
    const int sid = s >> 4, inner = s & 15;
    bz = sid / per_b_st;
    const int r2 = sid - bz * per_b_st;
    const int srt = r2 / scc, sct = r2 - srt * scc;
    rt = srt * 4 + (inner >> 2);
    ct = sct * 4 + (inner & 3);
  }

  const unsigned short* Ag = A + sAb * bz + (long)rt * 256 * K;
  const unsigned short* Bg = Bm + sBb * bz + (long)ct * 256 * K;

  // stage one half-tile (128x64) = 2 gl_lds/thread; LDS linear, src col
  // granule inverse-swizzled by the read involution (g ^= row&7).
  auto stA = [&](int buf, int half, int t) {
#pragma unroll
    for (int q = 0; q < 2; ++q) {
      int G = q * 512 + tid;
      int r = G >> 3, g = G & 7;
      gl_lds16(Ag + (long)(half * 128 + r) * K + t * 64 + ((g ^ (r & 7)) << 3),
               &lds[buf][0][half][G * 8]);
    }
  };
  auto stB = [&](int buf, int half, int t) {
#pragma unroll
    for (int q = 0; q < 2; ++q) {
      int G = q * 512 + tid;
      int r = G >> 3, g = G & 7;
      gl_lds16(Bg + (long)(half * 128 + r) * K + t * 64 + ((g ^ (r & 7)) << 3),
               &lds[buf][1][half][G * 8]);
    }
  };

  f32x4 acc[8][4];
#pragma unroll
  for (int m = 0; m < 8; ++m)
#pragma unroll
    for (int n = 0; n < 4; ++n) acc[m][n] = {0.f, 0.f, 0.f, 0.f};

  bf16x8 aF[8], aF2[8], bF0[4], bF1[4];
  auto rdA = [&](int buf, int mh, bf16x8* d) {
#pragma unroll
    for (int m = 0; m < 4; ++m) {
      int row = mh * 64 + m * 16 + r16;
#pragma unroll
      for (int ks = 0; ks < 2; ++ks)
        d[m * 2 + ks] = *(const bf16x8*)&lds[buf][0][wm]
            [row * 64 + ((((ks << 2) + kgrp) ^ (row & 7)) << 3)];
    }
  };
  auto rdB = [&](int buf, int nh, bf16x8* d) {
#pragma unroll
    for (int n = 0; n < 2; ++n) {
      int row = (wn & 1) * 64 + nh * 32 + n * 16 + r16;
#pragma unroll
      for (int ks = 0; ks < 2; ++ks)
        d[n * 2 + ks] = *(const bf16x8*)&lds[buf][1][wn >> 1]
            [row * 64 + ((((ks << 2) + kgrp) ^ (row & 7)) << 3)];
    }
  };
  auto mm = [&](bf16x8* af, bf16x8* bf, int mh, int nh) {
    __builtin_amdgcn_s_setprio(1);
#pragma unroll
    for (int ks = 0; ks < 2; ++ks)
#pragma unroll
      for (int m = 0; m < 4; ++m)
#pragma unroll
        for (int n = 0; n < 2; ++n)
          acc[mh * 4 + m][nh * 2 + n] = __builtin_amdgcn_mfma_f32_16x16x32_bf16(
              af[m * 2 + ks], bf[n * 2 + ks], acc[mh * 4 + m][nh * 2 + n], 0, 0, 0);
    __builtin_amdgcn_s_setprio(0);
  };

  const int NIT = K >> 7;  // 2 K-tiles (BK=64) per iteration
  stA(0, 0, 0); stA(0, 1, 0); stB(0, 0, 0); stB(0, 1, 0);
  stA(1, 0, 1); stA(1, 1, 1); stB(1, 0, 1); stB(1, 1, 1);
  VMC(8);
  BAR();
  SB0();

  for (int it = 0; it < NIT; ++it) {
    const int t1 = 2 * it + 1, t2 = 2 * it + 2, t3 = 2 * it + 3;
    const bool more = (it + 1 < NIT);
    // ---- ph1: t0 (mh0,nh0); tail-read bF1 for ph2 ----
    rdA(0, 0, aF); rdB(0, 0, bF0);
    if (it > 0) stA(1, 0, t1);
    BAR(); LGKM0();
    mm(aF, bF0, 0, 0);
    SB0();
    rdB(0, 1, bF1);        // overlaps MFMA drain (bF1 unused by ph1)
    BAR();
    // ---- ph2: t0 (mh0,nh1); tail-read aF2 for ph3 ----
    if (it > 0) stA(1, 1, t1);
    BAR(); LGKM0();
    mm(aF, bF1, 0, 1);
    SB0();
    rdA(0, 1, aF2);        // overlaps MFMA drain (aF2 distinct from aF)
    BAR();
    // ---- ph3: t0 (mh1,nh1) ---- buf0-B sealed at ph2 end
    if (more) stB(0, 0, t2);
    BAR(); LGKM0();
    mm(aF2, bF1, 1, 1);
    BAR();
    // ---- ph4: t0 (mh1,nh0) ---- vmcnt: tile t1 fully landed for ph5
    if (more) stB(0, 1, t2);
    BAR();
    mm(aF2, bF0, 1, 0);
    if (more) { VMC(4); } else { VMC(0); }
    BAR();
    // ---- ph5: t1 (mh0,nh0); tail-read bF1 ----
    rdA(1, 0, aF); rdB(1, 0, bF0);
    if (more) stA(0, 0, t2);
    BAR(); LGKM0();
    mm(aF, bF0, 0, 0);
    SB0();
    rdB(1, 1, bF1);
    BAR();
    // ---- ph6: t1 (mh0,nh1); tail-read aF2 ----
    if (more) stA(0, 1, t2);
    BAR(); LGKM0();
    mm(aF, bF1, 0, 1);
    SB0();
    rdA(1, 1, aF2);
    BAR();
    // ---- ph7: t1 (mh1,nh1) ---- buf1-B sealed at ph6 end
    if (more) stB(1, 0, t3);
    BAR(); LGKM0();
    mm(aF2, bF1, 1, 1);
    BAR();
    // ---- ph8: t1 (mh1,nh0) ---- vmcnt: tile t2 fully landed for next ph1
    if (more) stB(1, 1, t3);
    BAR();
    mm(aF2, bF0, 1, 0);
    if (more) { VMC(4); BAR(); }
  }

  const int row0 = rt * 256 + wm * 128;
  const int col0 = ct * 256 + wn * 64;
#pragma unroll
  for (int m = 0; m < 8; ++m) {
#pragma unroll
    for (int n = 0; n < 4; ++n) {
#pragma unroll
      for (int r = 0; r < 4; ++r) {
        float v = acc[m][n][r];
        int row = row0 + m * 16 + kgrp * 4 + r;  // C/D: col=lane&15, row=(lane>>4)*4+r
        int col = col0 + n * 16 + r16;
        if (MODE == 0) {
          float pp = __shfl_xor(v, 1);  // RoPE pair partner (col^1, same row/reg)
          int sel = col >> 10;          // 0=Q 1=K 2=V (uniform per 64-col wave slice)
          int lcol = col & 1023;
          if (sel < 2) {
            int pos = row & (C_LEN - 1);
            int i2 = lcol >> 1;
            float c = cosT[pos * (E_DIM / 2) + i2];
            float sn = sinT[pos * (E_DIM / 2) + i2];
            float rv = v * c + ((lcol & 1) ? pp * sn : -pp * sn);
            unsigned short* o = sel ? oK : oQ;
            o[(long)row * E_DIM + lcol] = f2bf(rv);
          } else {
            int b = row >> 12;
            int cc = row & (C_LEN - 1);
            oVt[(long)b * E_DIM * C_LEN + (long)lcol * C_LEN + cc] = f2bf(v);
          }
        } else if (MODE == 2) {
          float sc = v * 0.03125f + mask[(long)row * C_LEN + col];
          // f16 score packed into the first 8 KB of this row's f32 slot
          unsigned short* rowp =
              (unsigned short*)(oF + sOb * bz + (long)row * C_LEN);
          rowp[col] = f2h(sc);
        } else {
          oF[sOb * bz + (long)row * N + col] = v;
        }
      }
    }
  }
}

// -------- row softmax: read f16 scores (own row's first 8 KB), write f32
// weights in place + bf16 P copy. Row-local: no cross-row hazard. --------
__global__ __launch_bounds__(256) void softmax_rows(float* __restrict__ w,
                                                    unsigned short* __restrict__ pb) {
  long row = blockIdx.x;
  float* p = w + row * C_LEN;
  const unsigned short* ph = (const unsigned short*)p;  // f16 scores
  unsigned short* pbp = pb + row * C_LEN;
  int t = threadIdx.x;
  int wid = t >> 6;
  f32x4 v[4];
  float mx = -3.4e38f;
#pragma unroll
  for (int j = 0; j < 4; ++j) {
    u16x4 hb = *(const u16x4*)(ph + j * 1024 + t * 4);
    v[j].x = h2f(hb.x);
    v[j].y = h2f(hb.y);
    v[j].z = h2f(hb.z);
    v[j].w = h2f(hb.w);
    mx = fmaxf(mx, fmaxf(fmaxf(v[j].x, v[j].y), fmaxf(v[j].z, v[j].w)));
  }
#pragma unroll
  for (int o = 1; o < 64; o <<= 1) mx = fmaxf(mx, __shfl_xor(mx, o));
  __shared__ float redm[4];
  if ((t & 63) == 0) redm[wid] = mx;
  __syncthreads();
  mx = fmaxf(fmaxf(redm[0], redm[1]), fmaxf(redm[2], redm[3]));
  float sum = 0.f;
#pragma unroll
  for (int j = 0; j < 4; ++j) {
    v[j].x = __expf(v[j].x - mx);
    v[j].y = __expf(v[j].y - mx);
    v[j].z = __expf(v[j].z - mx);
    v[j].w = __expf(v[j].w - mx);
    sum += v[j].x + v[j].y + v[j].z + v[j].w;
  }
#pragma unroll
  for (int o = 1; o < 64; o <<= 1) sum += __shfl_xor(sum, o);
  __shared__ float reds[4];
  if ((t & 63) == 0) reds[wid] = sum;
  __syncthreads();
  sum = reds[0] + reds[1] + reds[2] + reds[3];
  float inv = 1.0f / sum;
  __syncthreads();  // all reads of this row's f16 data complete before stores
#pragma unroll
  for (int j = 0; j < 4; ++j) {
    v[j].x *= inv;
    v[j].y *= inv;
    v[j].z *= inv;
    v[j].w *= inv;
    __builtin_nontemporal_store(v[j], (f32x4*)(p + j * 1024 + t * 4));
    u16x4 o16 = {f2bf(v[j].x), f2bf(v[j].y), f2bf(v[j].z), f2bf(v[j].w)};
    *(u16x4*)(pbp + j * 1024 + t * 4) = o16;
  }
}

extern "C" void kernel_launch(void* const* d_in, const int* in_sizes, int n_in,
                              void* d_out, int out_size, void* d_ws, size_t ws_size,
                              hipStream_t stream) {
  const float* x = (const float*)d_in[0];
  const float* mask = (const float*)d_in[1];
  const float* Wq = (const float*)d_in[2];
  const float* Wk = (const float*)d_in[3];
  const float* Wv = (const float*)d_in[4];
  float* out = (float*)d_out;                           // [B][C][E]
  float* weights = out + (long)NBATCH * C_LEN * E_DIM;  // [B][C][C]

  char* ws = (char*)d_ws;
  const bool big = ws_size >= (160ull << 20);
  float* cosT = (float*)(ws);
  float* sinT = (float*)(ws + (8l << 20));
  unsigned short* x_bf = (unsigned short*)(ws + (16l << 20));
  unsigned short* W_bf = (unsigned short*)(ws + (48l << 20));  // [3072][1024] = Q|K|V
  unsigned short* Q_bf = (unsigned short*)(ws + (54l << 20));
  unsigned short* K_bf = (unsigned short*)(ws + (86l << 20));
  unsigned short* Vt = (unsigned short*)(ws + (big ? (128l << 20) : (118l << 20)));
  unsigned short* P_bf = (unsigned short*)(ws);

  dim3 blk(256);
  dim3 blk512(512);

  rope_table<<<dim3((C_LEN * (E_DIM / 2)) / 256), blk, 0, stream>>>(cosT, sinT);
  cvt_all<<<dim3(19456), blk, 0, stream>>>(x, Wq, Wk, Wv, x_bf, W_bf);

  // fused QKV projection: 64 rt x 12 ct = 768 blocks
  gemm8<0><<<dim3(768), blk512, 0, stream>>>(
      x_bf, W_bf, 0, 0, 0, 64, 12, E_DIM, 3 * E_DIM,
      Q_bf, K_bf, Vt, nullptr, cosT, sinT, nullptr);

  // scores = QK^T/32 + mask -> f16 packed into weights rows; 1024 blocks
  gemm8<2><<<dim3(1024), blk512, 0, stream>>>(
      Q_bf, K_bf, (long)C_LEN * E_DIM, (long)C_LEN * E_DIM, (long)C_LEN * C_LEN,
      16, 16, E_DIM, C_LEN, nullptr, nullptr, nullptr, weights, nullptr, nullptr, mask);

  if (big) {
    softmax_rows<<<dim3(NBATCH * C_LEN), blk, 0, stream>>>(weights, P_bf);
    // out = P @ V: 16 rt x 4 ct x 4 bz = 256 blocks
    gemm8<3><<<dim3(256), blk512, 0, stream>>>(
        P_bf, Vt, (long)C_LEN * C_LEN, (long)E_DIM * C_LEN, (long)C_LEN * E_DIM,
        16, 4, C_LEN, E_DIM, nullptr, nullptr, nullptr, out, nullptr, nullptr, nullptr);
  } else {
    for (int h = 0; h < 2; ++h) {
      float* wgt = weights + (long)h * 2 * C_LEN * C_LEN;
      softmax_rows<<<dim3(2 * C_LEN), blk, 0, stream>>>(wgt, P_bf);
      gemm8<3><<<dim3(128), blk512, 0, stream>>>(
          P_bf, Vt + (long)h * 2 * E_DIM * C_LEN, (long)C_LEN * C_LEN, (long)E_DIM * C_LEN,
          (long)C_LEN * E_DIM, 16, 4, C_LEN, E_DIM,
          nullptr, nullptr, nullptr, out + (long)h * 2 * C_LEN * E_DIM,
          nullptr, nullptr, nullptr);
    }
  }
}

// Round 16
// 586.072 us; speedup vs baseline: 1.2659x; 1.0003x over previous
//
#include <hip/hip_runtime.h>
#include <cstdint>

#define C_LEN 4096
#define E_DIM 1024
#define NBATCH 4

typedef __attribute__((ext_vector_type(4))) float f32x4;
typedef __attribute__((ext_vector_type(8))) short bf16x8;
typedef __attribute__((ext_vector_type(4))) unsigned short u16x4;

__device__ __forceinline__ unsigned short f2bf(float f) {
  uint32_t u = __builtin_bit_cast(uint32_t, f);
  return (unsigned short)((u + 0x7fffu + ((u >> 16) & 1u)) >> 16);
}

__device__ __forceinline__ unsigned short f2h(float f) {
  _Float16 h = (_Float16)f;
  return __builtin_bit_cast(unsigned short, h);
}
__device__ __forceinline__ float h2f(unsigned short u) {
  return (float)__builtin_bit_cast(_Float16, u);
}

__device__ __forceinline__ void gl_lds16(const void* g, void* l) {
  __builtin_amdgcn_global_load_lds(
      (const __attribute__((address_space(1))) void*)g,
      (__attribute__((address_space(3))) void*)l, 16, 0, 0);
}

#define BAR() __builtin_amdgcn_s_barrier()
#define VMC(n) asm volatile("s_waitcnt vmcnt(" #n ")" ::: "memory")

// -------- RoPE cos/sin table: [C][E/2] f32 each --------
__global__ __launch_bounds__(256) void rope_table(float* __restrict__ cosT,
                                                  float* __restrict__ sinT) {
  int idx = blockIdx.x * 256 + threadIdx.x;  // over C*E/2
  int pos = idx >> 9;
  int i = idx & 511;
  double inv = exp(((double)(-2 * i) / 1024.0) * 9.210340371976184);
  double a = (double)pos * inv;
  double r = a - 6.283185307179586 * rint(a * 0.15915494309189535);
  float rf = (float)r;
  float s, c;
  __sincosf(rf, &s, &c);
  cosT[idx] = c;
  sinT[idx] = s;
}

// -------- fused f32 -> bf16 convert for x, Wq, Wk, Wv --------
__global__ __launch_bounds__(256) void cvt_all(const float* __restrict__ x,
                                               const float* __restrict__ wq,
                                               const float* __restrict__ wk,
                                               const float* __restrict__ wv,
                                               unsigned short* __restrict__ x_bf,
                                               unsigned short* __restrict__ w_bf) {
  int b = blockIdx.x;
  const float* in;
  unsigned short* out;
  long off;
  if (b < 16384) { in = x; out = x_bf; off = (long)b * 1024; }
  else if (b < 17408) { in = wq; out = w_bf; off = (long)(b - 16384) * 1024; }
  else if (b < 18432) { in = wk; out = w_bf + (1l << 20); off = (long)(b - 17408) * 1024; }
  else { in = wv; out = w_bf + (2l << 20); off = (long)(b - 18432) * 1024; }
  long i = off + threadIdx.x * 4;
  f32x4 v = *(const f32x4*)(in + i);
  u16x4 o = {f2bf(v.x), f2bf(v.y), f2bf(v.z), f2bf(v.w)};
  *(u16x4*)(out + i) = o;
}

// ======== 256x256 8-phase GEMM, BK=64 — r15 structure, UNPINNED lgkm ========
// 512 threads = 8 waves (2M x 4N). LDS 128 KiB [buf(2)][A/B][half][128][64].
// vs r15: ALL lgkmcnt(0)+sched_barrier(0) pins removed from the K-loop. The
// ds_read->MFMA dependency is compiler-tracked (plain loads), so hipcc emits
// fine-grained partial lgkmcnt interleaved with MFMA issue (m97/m141
// evidence: full-drain pins cost throughput). Cross-wave safety unchanged:
// stage-vs-read hazards are covered by the raw barriers + counted vmcnt
// ledger, and each fragment is consumed (compiler-waited) before its wave's
// next barrier, so no read straddles a re-staged buffer.
// MODE 0: fused QKV projection (N=3072=[Q|K|V]); RoPE on Q/K, transpose V.
// MODE 2: *1/32 + mask, f16 scores packed into first 8KB of each f32 row slot.
// MODE 3: plain f32 out (PV).
template <int MODE>
__global__ __launch_bounds__(512, 1) void gemm8(
    const unsigned short* __restrict__ A, const unsigned short* __restrict__ Bm,
    long sAb, long sBb, long sOb, int nr, int nc, int K, int N,
    unsigned short* __restrict__ oQ, unsigned short* __restrict__ oK,
    unsigned short* __restrict__ oVt, float* __restrict__ oF,
    const float* __restrict__ cosT, const float* __restrict__ sinT,
    const float* __restrict__ mask) {
  __shared__ unsigned short lds[2][2][2][128 * 64];  // 128 KiB
  const int tid = threadIdx.x;
  const int lane = tid & 63;
  const int wid = tid >> 6;
  const int wm = wid >> 2, wn = wid & 3;  // 2M x 4N
  const int kgrp = lane >> 4, r16 = lane & 15;

  // XCD chunk (nwg%8==0) + 4x4 supertile decode (nr%4==0, nc%4==0)
  const int nwg = gridDim.x;
  const int lid = blockIdx.x;
  const int s = (lid & 7) * (nwg >> 3) + (lid >> 3);
  int bz, rt, ct;
  if (MODE == 2) {
    // batch innermost: 4 consecutive same-XCD blocks share (rt,ct) mask tile
    bz = s & 3;
    const int s4 = s >> 2;
    const int scc = nc >> 2;
    const int sid = s4 >> 4, inner = s4 & 15;
    const int srt = sid / scc, sct = sid - srt * scc;
    rt = srt * 4 + (inner >> 2);
    ct = sct * 4 + (inner & 3);
  } else {
    const int scc = nc >> 2;
    const int per_b_st = (nr >> 2) * scc;
    const int sid = s >> 4, inner = s & 15;
    bz = sid / per_b_st;
    const int r2 = sid - bz * per_b_st;
    const int srt = r2 / scc, sct = r2 - srt * scc;
    rt = srt * 4 + (inner >> 2);
    ct = sct * 4 + (inner & 3);
  }

  const unsigned short* Ag = A + sAb * bz + (long)rt * 256 * K;
  const unsigned short* Bg = Bm + sBb * bz + (long)ct * 256 * K;

  // stage one half-tile (128x64) = 2 gl_lds/thread; LDS linear, src col
  // granule inverse-swizzled by the read involution (g ^= row&7).
  auto stA = [&](int buf, int half, int t) {
#pragma unroll
    for (int q = 0; q < 2; ++q) {
      int G = q * 512 + tid;
      int r = G >> 3, g = G & 7;
      gl_lds16(Ag + (long)(half * 128 + r) * K + t * 64 + ((g ^ (r & 7)) << 3),
               &lds[buf][0][half][G * 8]);
    }
  };
  auto stB = [&](int buf, int half, int t) {
#pragma unroll
    for (int q = 0; q < 2; ++q) {
      int G = q * 512 + tid;
      int r = G >> 3, g = G & 7;
      gl_lds16(Bg + (long)(half * 128 + r) * K + t * 64 + ((g ^ (r & 7)) << 3),
               &lds[buf][1][half][G * 8]);
    }
  };

  f32x4 acc[8][4];
#pragma unroll
  for (int m = 0; m < 8; ++m)
#pragma unroll
    for (int n = 0; n < 4; ++n) acc[m][n] = {0.f, 0.f, 0.f, 0.f};

  bf16x8 aF[8], aF2[8], bF0[4], bF1[4];
  auto rdA = [&](int buf, int mh, bf16x8* d) {
#pragma unroll
    for (int m = 0; m < 4; ++m) {
      int row = mh * 64 + m * 16 + r16;
#pragma unroll
      for (int ks = 0; ks < 2; ++ks)
        d[m * 2 + ks] = *(const bf16x8*)&lds[buf][0][wm]
            [row * 64 + ((((ks << 2) + kgrp) ^ (row & 7)) << 3)];
    }
  };
  auto rdB = [&](int buf, int nh, bf16x8* d) {
#pragma unroll
    for (int n = 0; n < 2; ++n) {
      int row = (wn & 1) * 64 + nh * 32 + n * 16 + r16;
#pragma unroll
      for (int ks = 0; ks < 2; ++ks)
        d[n * 2 + ks] = *(const bf16x8*)&lds[buf][1][wn >> 1]
            [row * 64 + ((((ks << 2) + kgrp) ^ (row & 7)) << 3)];
    }
  };
  auto mm = [&](bf16x8* af, bf16x8* bf, int mh, int nh) {
    __builtin_amdgcn_s_setprio(1);
#pragma unroll
    for (int ks = 0; ks < 2; ++ks)
#pragma unroll
      for (int m = 0; m < 4; ++m)
#pragma unroll
        for (int n = 0; n < 2; ++n)
          acc[mh * 4 + m][nh * 2 + n] = __builtin_amdgcn_mfma_f32_16x16x32_bf16(
              af[m * 2 + ks], bf[n * 2 + ks], acc[mh * 4 + m][nh * 2 + n], 0, 0, 0);
    __builtin_amdgcn_s_setprio(0);
  };

  const int NIT = K >> 7;  // 2 K-tiles (BK=64) per iteration
  stA(0, 0, 0); stA(0, 1, 0); stB(0, 0, 0); stB(0, 1, 0);
  stA(1, 0, 1); stA(1, 1, 1); stB(1, 0, 1); stB(1, 1, 1);
  VMC(8);
  BAR();

  for (int it = 0; it < NIT; ++it) {
    const int t1 = 2 * it + 1, t2 = 2 * it + 2, t3 = 2 * it + 3;
    const bool more = (it + 1 < NIT);
    // ---- ph1: t0 (mh0,nh0); tail-read bF1 for ph2 ----
    rdA(0, 0, aF); rdB(0, 0, bF0);
    if (it > 0) stA(1, 0, t1);
    BAR();
    mm(aF, bF0, 0, 0);
    rdB(0, 1, bF1);        // interleaves with MFMA drain (bF1 unused by ph1)
    BAR();
    // ---- ph2: t0 (mh0,nh1); tail-read aF2 for ph3 ----
    if (it > 0) stA(1, 1, t1);
    BAR();
    mm(aF, bF1, 0, 1);
    rdA(0, 1, aF2);        // interleaves with MFMA drain (aF2 distinct)
    BAR();
    // ---- ph3: t0 (mh1,nh1) ---- buf0-B sealed at ph2 end
    if (more) stB(0, 0, t2);
    BAR();
    mm(aF2, bF1, 1, 1);
    BAR();
    // ---- ph4: t0 (mh1,nh0) ---- vmcnt: tile t1 fully landed for ph5
    if (more) stB(0, 1, t2);
    BAR();
    mm(aF2, bF0, 1, 0);
    if (more) { VMC(4); } else { VMC(0); }
    BAR();
    // ---- ph5: t1 (mh0,nh0); tail-read bF1 ----
    rdA(1, 0, aF); rdB(1, 0, bF0);
    if (more) stA(0, 0, t2);
    BAR();
    mm(aF, bF0, 0, 0);
    rdB(1, 1, bF1);
    BAR();
    // ---- ph6: t1 (mh0,nh1); tail-read aF2 ----
    if (more) stA(0, 1, t2);
    BAR();
    mm(aF, bF1, 0, 1);
    rdA(1, 1, aF2);
    BAR();
    // ---- ph7: t1 (mh1,nh1) ---- buf1-B sealed at ph6 end
    if (more) stB(1, 0, t3);
    BAR();
    mm(aF2, bF1, 1, 1);
    BAR();
    // ---- ph8: t1 (mh1,nh0) ---- vmcnt: tile t2 fully landed for next ph1
    if (more) stB(1, 1, t3);
    BAR();
    mm(aF2, bF0, 1, 0);
    if (more) { VMC(4); BAR(); }
  }

  const int row0 = rt * 256 + wm * 128;
  const int col0 = ct * 256 + wn * 64;
#pragma unroll
  for (int m = 0; m < 8; ++m) {
#pragma unroll
    for (int n = 0; n < 4; ++n) {
#pragma unroll
      for (int r = 0; r < 4; ++r) {
        float v = acc[m][n][r];
        int row = row0 + m * 16 + kgrp * 4 + r;  // C/D: col=lane&15, row=(lane>>4)*4+r
        int col = col0 + n * 16 + r16;
        if (MODE == 0) {
          float pp = __shfl_xor(v, 1);  // RoPE pair partner (col^1, same row/reg)
          int sel = col >> 10;          // 0=Q 1=K 2=V (uniform per 64-col wave slice)
          int lcol = col & 1023;
          if (sel < 2) {
            int pos = row & (C_LEN - 1);
            int i2 = lcol >> 1;
            float c = cosT[pos * (E_DIM / 2) + i2];
            float sn = sinT[pos * (E_DIM / 2) + i2];
            float rv = v * c + ((lcol & 1) ? pp * sn : -pp * sn);
            unsigned short* o = sel ? oK : oQ;
            o[(long)row * E_DIM + lcol] = f2bf(rv);
          } else {
            int b = row >> 12;
            int cc = row & (C_LEN - 1);
            oVt[(long)b * E_DIM * C_LEN + (long)lcol * C_LEN + cc] = f2bf(v);
          }
        } else if (MODE == 2) {
          float sc = v * 0.03125f + mask[(long)row * C_LEN + col];
          // f16 score packed into the first 8 KB of this row's f32 slot
          unsigned short* rowp =
              (unsigned short*)(oF + sOb * bz + (long)row * C_LEN);
          rowp[col] = f2h(sc);
        } else {
          oF[sOb * bz + (long)row * N + col] = v;
        }
      }
    }
  }
}

// -------- row softmax: read f16 scores (own row's first 8 KB), write f32
// weights in place + bf16 P copy. Row-local: no cross-row hazard. --------
__global__ __launch_bounds__(256) void softmax_rows(float* __restrict__ w,
                                                    unsigned short* __restrict__ pb) {
  long row = blockIdx.x;
  float* p = w + row * C_LEN;
  const unsigned short* ph = (const unsigned short*)p;  // f16 scores
  unsigned short* pbp = pb + row * C_LEN;
  int t = threadIdx.x;
  int wid = t >> 6;
  f32x4 v[4];
  float mx = -3.4e38f;
#pragma unroll
  for (int j = 0; j < 4; ++j) {
    u16x4 hb = *(const u16x4*)(ph + j * 1024 + t * 4);
    v[j].x = h2f(hb.x);
    v[j].y = h2f(hb.y);
    v[j].z = h2f(hb.z);
    v[j].w = h2f(hb.w);
    mx = fmaxf(mx, fmaxf(fmaxf(v[j].x, v[j].y), fmaxf(v[j].z, v[j].w)));
  }
#pragma unroll
  for (int o = 1; o < 64; o <<= 1) mx = fmaxf(mx, __shfl_xor(mx, o));
  __shared__ float redm[4];
  if ((t & 63) == 0) redm[wid] = mx;
  __syncthreads();
  mx = fmaxf(fmaxf(redm[0], redm[1]), fmaxf(redm[2], redm[3]));
  float sum = 0.f;
#pragma unroll
  for (int j = 0; j < 4; ++j) {
    v[j].x = __expf(v[j].x - mx);
    v[j].y = __expf(v[j].y - mx);
    v[j].z = __expf(v[j].z - mx);
    v[j].w = __expf(v[j].w - mx);
    sum += v[j].x + v[j].y + v[j].z + v[j].w;
  }
#pragma unroll
  for (int o = 1; o < 64; o <<= 1) sum += __shfl_xor(sum, o);
  __shared__ float reds[4];
  if ((t & 63) == 0) reds[wid] = sum;
  __syncthreads();
  sum = reds[0] + reds[1] + reds[2] + reds[3];
  float inv = 1.0f / sum;
  __syncthreads();  // all reads of this row's f16 data complete before stores
#pragma unroll
  for (int j = 0; j < 4; ++j) {
    v[j].x *= inv;
    v[j].y *= inv;
    v[j].z *= inv;
    v[j].w *= inv;
    __builtin_nontemporal_store(v[j], (f32x4*)(p + j * 1024 + t * 4));
    u16x4 o16 = {f2bf(v[j].x), f2bf(v[j].y), f2bf(v[j].z), f2bf(v[j].w)};
    *(u16x4*)(pbp + j * 1024 + t * 4) = o16;
  }
}

extern "C" void kernel_launch(void* const* d_in, const int* in_sizes, int n_in,
                              void* d_out, int out_size, void* d_ws, size_t ws_size,
                              hipStream_t stream) {
  const float* x = (const float*)d_in[0];
  const float* mask = (const float*)d_in[1];
  const float* Wq = (const float*)d_in[2];
  const float* Wk = (const float*)d_in[3];
  const float* Wv = (const float*)d_in[4];
  float* out = (float*)d_out;                           // [B][C][E]
  float* weights = out + (long)NBATCH * C_LEN * E_DIM;  // [B][C][C]

  char* ws = (char*)d_ws;
  const bool big = ws_size >= (160ull << 20);
  float* cosT = (float*)(ws);
  float* sinT = (float*)(ws + (8l << 20));
  unsigned short* x_bf = (unsigned short*)(ws + (16l << 20));
  unsigned short* W_bf = (unsigned short*)(ws + (48l << 20));  // [3072][1024] = Q|K|V
  unsigned short* Q_bf = (unsigned short*)(ws + (54l << 20));
  unsigned short* K_bf = (unsigned short*)(ws + (86l << 20));
  unsigned short* Vt = (unsigned short*)(ws + (big ? (128l << 20) : (118l << 20)));
  unsigned short* P_bf = (unsigned short*)(ws);

  dim3 blk(256);
  dim3 blk512(512);

  rope_table<<<dim3((C_LEN * (E_DIM / 2)) / 256), blk, 0, stream>>>(cosT, sinT);
  cvt_all<<<dim3(19456), blk, 0, stream>>>(x, Wq, Wk, Wv, x_bf, W_bf);

  // fused QKV projection: 64 rt x 12 ct = 768 blocks
  gemm8<0><<<dim3(768), blk512, 0, stream>>>(
      x_bf, W_bf, 0, 0, 0, 64, 12, E_DIM, 3 * E_DIM,
      Q_bf, K_bf, Vt, nullptr, cosT, sinT, nullptr);

  // scores = QK^T/32 + mask -> f16 packed into weights rows; 1024 blocks
  gemm8<2><<<dim3(1024), blk512, 0, stream>>>(
      Q_bf, K_bf, (long)C_LEN * E_DIM, (long)C_LEN * E_DIM, (long)C_LEN * C_LEN,
      16, 16, E_DIM, C_LEN, nullptr, nullptr, nullptr, weights, nullptr, nullptr, mask);

  if (big) {
    softmax_rows<<<dim3(NBATCH * C_LEN), blk, 0, stream>>>(weights, P_bf);
    // out = P @ V: 16 rt x 4 ct x 4 bz = 256 blocks
    gemm8<3><<<dim3(256), blk512, 0, stream>>>(
        P_bf, Vt, (long)C_LEN * C_LEN, (long)E_DIM * C_LEN, (long)C_LEN * E_DIM,
        16, 4, C_LEN, E_DIM, nullptr, nullptr, nullptr, out, nullptr, nullptr, nullptr);
  } else {
    for (int h = 0; h < 2; ++h) {
      float* wgt = weights + (long)h * 2 * C_LEN * C_LEN;
      softmax_rows<<<dim3(2 * C_LEN), blk, 0, stream>>>(wgt, P_bf);
      gemm8<3><<<dim3(128), blk512, 0, stream>>>(
          P_bf, Vt + (long)h * 2 * E_DIM * C_LEN, (long)C_LEN * C_LEN, (long)E_DIM * C_LEN,
          (long)C_LEN * E_DIM, 16, 4, C_LEN, E_DIM,
          nullptr, nullptr, nullptr, out + (long)h * 2 * C_LEN * E_DIM,
          nullptr, nullptr, nullptr);
    }
  }
}